// Round 2
// baseline (773.830 us; speedup 1.0000x reference)
//
#include <hip/hip_runtime.h>
#include <cstdint>
#include <cstddef>

// GAT forward: query = ufea@W^T + b; S = leaky2((q@inter^T)/sqrt(D)) masked by adj;
// out = softmax(S) @ inter.   N=10000 users, M=12000 items, D=128.
// R9: barrier-free fused kernel.
//  kvg (6.2 MB, chunk slice 385 KB) is L2-resident per XCD (chunk-major grid ->
//  chunk c lands on XCD c%8). So LDS staging of K/V was pure overhead: its two
//  __syncthreads per tile each drain vmcnt(0) (the m97-structure stall).
//  Now B-frags are read DIRECTLY from kvg (identical fragment-image layout),
//  Kbuf/Vbuf and ALL barriers are gone; P stays in per-wave LDS (no cross-wave
//  sharing). Waves slip independently; s_setprio(1) wraps MFMA clusters (T5).

#define N_USERS 10000
#define N_ITEMS 12000
#define HD      128
#define QROWS   10112      // 632*16 padded user rows
#define NCHUNK  16
#define TILE    64
#define NTILES  188        // ceil(12000/64); tile 187 has 32 valid items (zero-padded)
#define UBLOCKS 79         // fused user-blocks of 128
#define QBLOCKS 632        // query blocks of 16 users

typedef __bf16 bf16x8 __attribute__((ext_vector_type(8)));
typedef __bf16 bf16x4 __attribute__((ext_vector_type(4)));
typedef float  f32x4  __attribute__((ext_vector_type(4)));
typedef int    i32x4  __attribute__((ext_vector_type(4)));

// ---------------- inter -> kvg tile-chunk-major bf16 fragment image ----------------
// kvg layout per tile t (32KB): 32 chunks x 512 halves.
//   chunk c<16  (K): c=nt*4+kk, element[lane= qd*16+n][e] = K[t*64 + 4n+nt][kk*32+qd*8+e]
//   chunk 16+cc (V): cc=dt*2+kc, element[lane][e]        = inter[t*64+kc*32+qd*8+e][dt*16+n]
// Invalid items (>=12000) zero-filled -> fused needs no row clamps for K/V.
__global__ __launch_bounds__(256) void cast_inter_kernel(const float* __restrict__ inter,
                                                         __bf16* __restrict__ kvg) {
    __shared__ __bf16 Tl[128 * 72];   // [d][item_local], pitch 72 (16B-aligned rows)
    const int t  = threadIdx.x;
    const int tile = blockIdx.x;
    const int i0 = tile * 64;
    for (int it = 0; it < 8; ++it) {
        int g   = it * 256 + t;
        int row = g >> 5;            // 0..63 item_local
        int d   = (g & 31) * 4;      // 0..124
        int item = i0 + row;
        if (item < N_ITEMS) {
            f32x4 v = *(const f32x4*)(inter + (size_t)item * HD + d);
            Tl[(d + 0) * 72 + row] = (__bf16)v.x;
            Tl[(d + 1) * 72 + row] = (__bf16)v.y;
            Tl[(d + 2) * 72 + row] = (__bf16)v.z;
            Tl[(d + 3) * 72 + row] = (__bf16)v.w;
        } else {
            Tl[(d + 0) * 72 + row] = (__bf16)0.f;
            Tl[(d + 1) * 72 + row] = (__bf16)0.f;
            Tl[(d + 2) * 72 + row] = (__bf16)0.f;
            Tl[(d + 3) * 72 + row] = (__bf16)0.f;
        }
    }
    __syncthreads();
    const int lane = t & 63, wave = t >> 6;
    const int n = lane & 15, qd = lane >> 4;
    __bf16* tbase = kvg + (size_t)tile * (32 * 512);
    // K chunks: re-read inter rows from global (L2-hot after pass 1), cast to bf16
    #pragma unroll
    for (int j = 0; j < 4; ++j) {
        const int c = wave * 4 + j;            // nt = wave, kk = j
        int row = i0 + 4 * n + wave;
        bf16x8 o;
        if (row < N_ITEMS) {
            const float* p = inter + (size_t)row * HD + j * 32 + qd * 8;
            f32x4 lo = *(const f32x4*)p, hi = *(const f32x4*)(p + 4);
            o[0]=(__bf16)lo.x; o[1]=(__bf16)lo.y; o[2]=(__bf16)lo.z; o[3]=(__bf16)lo.w;
            o[4]=(__bf16)hi.x; o[5]=(__bf16)hi.y; o[6]=(__bf16)hi.z; o[7]=(__bf16)hi.w;
        } else {
            #pragma unroll
            for (int e = 0; e < 8; ++e) o[e] = (__bf16)0.f;
        }
        *(bf16x8*)(tbase + (size_t)c * 512 + lane * 8) = o;
    }
    // V chunks: from the LDS transpose
    #pragma unroll
    for (int j = 0; j < 4; ++j) {
        const int cc = wave * 4 + j;           // dt = cc>>1, kc = cc&1
        const int dt = cc >> 1, kc = cc & 1;
        bf16x8 v = *(const bf16x8*)&Tl[(dt * 16 + n) * 72 + kc * 32 + qd * 8];
        *(bf16x8*)(tbase + (size_t)(16 + cc) * 512 + lane * 8) = v;
    }
}

// ---------------- query = ufea @ W^T + b  (bf16 MFMA, output bf16) ----------------
// 632 blocks x 16 users; the 4 waves of a block split the 8 output nt-tiles.
__global__ __launch_bounds__(256) void query_kernel(const float* __restrict__ ufea,
                                                    const float* __restrict__ W,
                                                    const float* __restrict__ bias,
                                                    __bf16* __restrict__ qg) {
    const int lane = threadIdx.x & 63, wave = threadIdx.x >> 6;
    const int n = lane & 15, qd = lane >> 4;
    const int user0 = blockIdx.x * 16;
    int arow = user0 + n; if (arow > N_USERS - 1) arow = N_USERS - 1;

    bf16x8 af[4];
    #pragma unroll
    for (int kk = 0; kk < 4; ++kk) {
        const float* p = ufea + (size_t)arow * HD + kk * 32 + qd * 8;
        f32x4 lo = *(const f32x4*)p, hi = *(const f32x4*)(p + 4);
        bf16x8 a;
        a[0]=(__bf16)lo.x; a[1]=(__bf16)lo.y; a[2]=(__bf16)lo.z; a[3]=(__bf16)lo.w;
        a[4]=(__bf16)hi.x; a[5]=(__bf16)hi.y; a[6]=(__bf16)hi.z; a[7]=(__bf16)hi.w;
        af[kk] = a;
    }
    #pragma unroll
    for (int h = 0; h < 2; ++h) {
        const int nt = wave * 2 + h;
        f32x4 acc = {0.f, 0.f, 0.f, 0.f};
        #pragma unroll
        for (int kk = 0; kk < 4; ++kk) {
            const float* p = W + (size_t)(nt * 16 + n) * HD + kk * 32 + qd * 8;
            f32x4 lo = *(const f32x4*)p, hi = *(const f32x4*)(p + 4);
            bf16x8 b;
            b[0]=(__bf16)lo.x; b[1]=(__bf16)lo.y; b[2]=(__bf16)lo.z; b[3]=(__bf16)lo.w;
            b[4]=(__bf16)hi.x; b[5]=(__bf16)hi.y; b[6]=(__bf16)hi.z; b[7]=(__bf16)hi.w;
            acc = __builtin_amdgcn_mfma_f32_16x16x32_bf16(af[kk], b, acc, 0, 0, 0);
        }
        const float bv = bias[nt * 16 + n];
        #pragma unroll
        for (int r = 0; r < 4; ++r) {
            int row = user0 + qd * 4 + r;      // < QROWS always (user0 <= 10096)
            qg[(size_t)row * HD + nt * 16 + n] = (__bf16)(acc[r] + bv);
        }
    }
}

// ---------------- fused: S = q@k^T, mask+leaky+exp, O += P@V, l += rowsum ----------------
// Barrier-free. Wave = 32 users (two 16-user groups sharing every B-frag, now
// loaded once into VGPRs and feeding 2 MFMAs). B-frags read directly from the
// L2-resident kvg fragment image. P per-wave in LDS. adj prefetched 1 tile ahead.
__global__ __launch_bounds__(256, 2) void fused_kernel(const __bf16* __restrict__ qg,
                                                       const __bf16* __restrict__ kvg,
                                                       const int* __restrict__ adj,
                                                       float* __restrict__ Opart,
                                                       float* __restrict__ lpart) {
    __shared__ __bf16 Pl[4][32 * 72];     // per-wave P: [user 0..31][item 0..63], pitch 72
    const int lane = threadIdx.x & 63, wave = threadIdx.x >> 6;
    const int n = lane & 15, qd = lane >> 4;
    const int user0 = blockIdx.y * 128 + wave * 32;   // wave covers users user0..user0+31
    const int chunk = blockIdx.x;          // chunk-major grid: chunk -> XCD chunk%8 (L2 affinity)
    const int t0 = (chunk * NTILES) / NCHUNK;
    const int t1 = ((chunk + 1) * NTILES) / NCHUNK;
    const float SC = (float)(1.4426950408889634 * 0.08838834764831845); // log2(e)/sqrt(128)

    bf16x8 qf[2][4];
    #pragma unroll
    for (int g = 0; g < 2; ++g)
        #pragma unroll
        for (int kk = 0; kk < 4; ++kk)
            qf[g][kk] = *(const bf16x8*)(qg + (size_t)(user0 + g * 16 + n) * HD + kk * 32 + qd * 8);

    f32x4 Oacc[2][8];
    #pragma unroll
    for (int g = 0; g < 2; ++g)
        #pragma unroll
        for (int dt = 0; dt < 8; ++dt) Oacc[g][dt] = (f32x4){0.f, 0.f, 0.f, 0.f};
    float lacc[2][4] = {{0.f,0.f,0.f,0.f},{0.f,0.f,0.f,0.f}};

    int adjOff[2][4];   // element offsets (10000*12000 < 2^31)
    #pragma unroll
    for (int g = 0; g < 2; ++g)
        #pragma unroll
        for (int r = 0; r < 4; ++r) {
            int u = user0 + g * 16 + qd * 4 + r;
            if (u > N_USERS - 1) u = N_USERS - 1;
            adjOff[g][r] = u * N_ITEMS;
        }
    __bf16* pw = &Pl[wave][0];

    // adj ping-pong prefetch registers (avA used / avB prefetched, then swap)
    i32x4 avA[2][4], avB[2][4];
    {   // prologue: adj for tile t0
        int col4 = t0 * TILE + 4 * n;
        if (col4 > N_ITEMS - 4) col4 = N_ITEMS - 4;
        #pragma unroll
        for (int g = 0; g < 2; ++g)
            #pragma unroll
            for (int r = 0; r < 4; ++r)
                avA[g][r] = __builtin_nontemporal_load((const i32x4*)(adj + adjOff[g][r] + col4));
    }

    auto tile_iter = [&](int T, i32x4 (&avu)[2][4], i32x4 (&avp)[2][4]) {
        const int j0 = T * TILE;
        const __bf16* tb = kvg + (size_t)T * (32 * 512);

        // QK: 16 B-frag global loads (L2-hit), each feeding both user groups
        f32x4 S[2][4];
        #pragma unroll
        for (int g = 0; g < 2; ++g)
            #pragma unroll
            for (int nt = 0; nt < 4; ++nt) S[g][nt] = (f32x4){0.f, 0.f, 0.f, 0.f};
        __builtin_amdgcn_s_setprio(1);
        #pragma unroll
        for (int nt = 0; nt < 4; ++nt) {
            #pragma unroll
            for (int kk = 0; kk < 4; ++kk) {
                bf16x8 b = *(const bf16x8*)(tb + (size_t)(nt * 4 + kk) * 512 + lane * 8);
                S[0][nt] = __builtin_amdgcn_mfma_f32_16x16x32_bf16(qf[0][kk], b, S[0][nt], 0, 0, 0);
                S[1][nt] = __builtin_amdgcn_mfma_f32_16x16x32_bf16(qf[1][kk], b, S[1][nt], 0, 0, 0);
            }
        }
        __builtin_amdgcn_s_setprio(0);

        // prefetch NEXT tile's adj into avp (latency hides under mask+PV compute)
        {
            int tn = T + 1; if (tn > t1 - 1) tn = t1 - 1;
            int col4 = tn * TILE + 4 * n;
            if (col4 > N_ITEMS - 4) col4 = N_ITEMS - 4;
            #pragma unroll
            for (int g = 0; g < 2; ++g)
                #pragma unroll
                for (int r = 0; r < 4; ++r)
                    avp[g][r] = __builtin_nontemporal_load((const i32x4*)(adj + adjOff[g][r] + col4));
        }

        // mask + leaky2 + exp2 -> P quads (bf16x4 = items 4n..4n+3 of row)
        #pragma unroll
        for (int g = 0; g < 2; ++g) {
            #pragma unroll
            for (int r = 0; r < 4; ++r) {
                bf16x4 pk;
                #pragma unroll
                for (int nt = 0; nt < 4; ++nt) {
                    float s = S[g][nt][r] * SC;
                    s = fminf(s, s + s);            // leaky_relu(slope 2), pre-scaled
                    const bool on = (j0 + 4 * n + nt < N_ITEMS) && (avu[g][r][nt] > 0);
                    float p = on ? __builtin_amdgcn_exp2f(s) : 0.f;
                    lacc[g][r] += p;
                    pk[nt] = (__bf16)p;
                }
                *(bf16x4*)(pw + (g * 16 + qd * 4 + r) * 72 + 4 * n) = pk;
            }
        }

        // PV: 16 V B-frag global loads (L2-hit), each feeding both groups
        #pragma unroll
        for (int kc = 0; kc < 2; ++kc) {
            bf16x8 af0 = *(const bf16x8*)(pw + (0 * 16 + n) * 72 + kc * 32 + qd * 8);
            bf16x8 af1 = *(const bf16x8*)(pw + (1 * 16 + n) * 72 + kc * 32 + qd * 8);
            __builtin_amdgcn_s_setprio(1);
            #pragma unroll
            for (int dt = 0; dt < 8; ++dt) {
                bf16x8 b = *(const bf16x8*)(tb + (size_t)(16 + dt * 2 + kc) * 512 + lane * 8);
                Oacc[0][dt] = __builtin_amdgcn_mfma_f32_16x16x32_bf16(af0, b, Oacc[0][dt], 0, 0, 0);
                Oacc[1][dt] = __builtin_amdgcn_mfma_f32_16x16x32_bf16(af1, b, Oacc[1][dt], 0, 0, 0);
            }
            __builtin_amdgcn_s_setprio(0);
        }
    };

    int t = t0;
    while (true) {
        tile_iter(t, avA, avB); ++t; if (t >= t1) break;
        tile_iter(t, avB, avA); ++t; if (t >= t1) break;
    }

    // reduce l across the 16 lanes of each quad (lanes jointly cover all items)
    #pragma unroll
    for (int g = 0; g < 2; ++g)
        #pragma unroll
        for (int r = 0; r < 4; ++r) {
            float v = lacc[g][r];
            v += __shfl_xor(v, 1);
            v += __shfl_xor(v, 2);
            v += __shfl_xor(v, 4);
            v += __shfl_xor(v, 8);
            lacc[g][r] = v;
        }
    const size_t cb = (size_t)chunk * QROWS;
    #pragma unroll
    for (int g = 0; g < 2; ++g)
        #pragma unroll
        for (int r = 0; r < 4; ++r) {
            const int user = user0 + g * 16 + qd * 4 + r;
            if (user < N_USERS) {
                #pragma unroll
                for (int dt = 0; dt < 8; ++dt)
                    Opart[(cb + user) * HD + dt * 16 + n] = Oacc[g][dt][r];
                if (n == 0) lpart[cb + user] = lacc[g][r];
            }
        }
}

// ---------------- combine partials: out = (sum_c O_c) / (sum_c l_c) ----------------
__global__ __launch_bounds__(256) void combine_kernel(const float* __restrict__ Opart,
                                                      const float* __restrict__ lpart,
                                                      float* __restrict__ out) {
    const int g = blockIdx.x * 256 + threadIdx.x;   // 323584 threads exactly
    const int base = g * 4;
    const int user = base >> 7;
    const int d = base & 127;
    f32x4 acc = {0.f, 0.f, 0.f, 0.f};
    float l = 0.f;
    #pragma unroll
    for (int c = 0; c < NCHUNK; ++c) {
        acc += *(const f32x4*)(Opart + ((size_t)c * QROWS + user) * HD + d);
        l += lpart[(size_t)c * QROWS + user];
    }
    if (user < N_USERS) {
        f32x4 res = acc / l;
        *(f32x4*)(out + (size_t)user * HD + d) = res;
    }
}

extern "C" void kernel_launch(void* const* d_in, const int* in_sizes, int n_in,
                              void* d_out, int out_size, void* d_ws, size_t ws_size,
                              hipStream_t stream) {
    const float* ufea = (const float*)d_in[0];
    const float* inter = (const float*)d_in[1];
    const int*   adj  = (const int*)d_in[2];
    const float* W    = (const float*)d_in[3];
    const float* bias = (const float*)d_in[4];
    float* out = (float*)d_out;

    char* ws = (char*)d_ws;
    // layout (bytes):
    //   kvg   : 188*32*512*2      = 6,160,384   (tile-chunk-major K/V fragment image)
    //   qg    : 10112*128*2       = 2,588,672
    //   Opart : 16*10112*128*4    = 82,837,504
    //   lpart : 16*10112*4        = 647,168          total ~92.2 MB
    __bf16* kvg  = (__bf16*)(ws);
    __bf16* qg   = (__bf16*)(ws + 6160384);
    float*  Opart = (float*)(ws + 8749056);
    float*  lpart = (float*)(ws + 91586560);

    cast_inter_kernel<<<dim3(NTILES), dim3(256), 0, stream>>>(inter, kvg);
    query_kernel<<<dim3(QBLOCKS), dim3(256), 0, stream>>>(ufea, W, bias, qg);
    fused_kernel<<<dim3(NCHUNK, UBLOCKS), dim3(256), 0, stream>>>(qg, kvg, adj, Opart, lpart);
    combine_kernel<<<dim3(1264), dim3(256), 0, stream>>>(Opart, lpart, out);
}

// Round 3
// 663.855 us; speedup vs baseline: 1.1657x; 1.1657x over previous
//
#include <hip/hip_runtime.h>
#include <cstdint>
#include <cstddef>

// GAT forward: query = ufea@W^T + b; S = leaky2((q@inter^T)/sqrt(D)) masked by adj;
// out = softmax(S) @ inter.   N=10000 users, M=12000 items, D=128.
// R10: back to R8's LDS-staged structure (R9's direct-L2 reads regressed +84us),
// plus three levers:
//  (1) Pipelined staging: Kbuf double-buffered; K(T+1) issued BEFORE QK(T) so it
//      flies under ~1000cy of compute before barrier1 drains it. V single-buffered
//      but staged AFTER the post-PV barrier -> flies under next tile's QK+mask.
//      No barrier drains a just-issued load (removes the m97-structure stall).
//  (2) NCHUNK 16->12: 948 blocks = 1.85 rounds of 512 resident (93% util vs 82%).
//  (3) cast+query merged into one prep kernel (they're independent).

#define N_USERS 10000
#define N_ITEMS 12000
#define HD      128
#define QROWS   10112      // 632*16 padded user rows
#define NCHUNK  12
#define TILE    64
#define NTILES  188        // ceil(12000/64); tile 187 has 32 valid items (zero-padded)
#define UBLOCKS 79         // fused user-blocks of 128
#define QBLOCKS 632        // query blocks of 16 users

typedef __bf16 bf16x8 __attribute__((ext_vector_type(8)));
typedef __bf16 bf16x4 __attribute__((ext_vector_type(4)));
typedef float  f32x4  __attribute__((ext_vector_type(4)));
typedef int    i32x4  __attribute__((ext_vector_type(4)));

typedef const __attribute__((address_space(1))) unsigned int g_u32;
typedef __attribute__((address_space(3))) unsigned int l_u32;

// ---------------- prep: inter -> kvg fragment image  +  query = ufea@W^T + b ----------------
// kvg layout per tile t (32KB): 32 chunks x 512 halves.
//   chunk c<16  (K): c=nt*4+kk, element[lane= qd*16+n][e] = K[t*64 + 4n+nt][kk*32+qd*8+e]
//   chunk 16+cc (V): cc=dt*2+kc, element[lane][e]        = inter[t*64+kc*32+qd*8+e][dt*16+n]
// Invalid items (>=12000) zero-filled -> fused needs no row clamps for K/V.
__global__ __launch_bounds__(256) void prep_kernel(const float* __restrict__ inter,
                                                   const float* __restrict__ ufea,
                                                   const float* __restrict__ W,
                                                   const float* __restrict__ bias,
                                                   __bf16* __restrict__ kvg,
                                                   __bf16* __restrict__ qg) {
    __shared__ __bf16 Tl[128 * 72];   // [d][item_local], pitch 72 (16B-aligned rows)
    const int t = threadIdx.x;
    const int lane = t & 63, wave = t >> 6;
    const int n = lane & 15, qd = lane >> 4;

    if (blockIdx.x < NTILES) {
        // ---- cast path ----
        const int tile = blockIdx.x;
        const int i0 = tile * 64;
        for (int it = 0; it < 8; ++it) {
            int g   = it * 256 + t;
            int row = g >> 5;            // 0..63 item_local
            int d   = (g & 31) * 4;      // 0..124
            int item = i0 + row;
            if (item < N_ITEMS) {
                f32x4 v = *(const f32x4*)(inter + (size_t)item * HD + d);
                Tl[(d + 0) * 72 + row] = (__bf16)v.x;
                Tl[(d + 1) * 72 + row] = (__bf16)v.y;
                Tl[(d + 2) * 72 + row] = (__bf16)v.z;
                Tl[(d + 3) * 72 + row] = (__bf16)v.w;
            } else {
                Tl[(d + 0) * 72 + row] = (__bf16)0.f;
                Tl[(d + 1) * 72 + row] = (__bf16)0.f;
                Tl[(d + 2) * 72 + row] = (__bf16)0.f;
                Tl[(d + 3) * 72 + row] = (__bf16)0.f;
            }
        }
        __syncthreads();
        __bf16* tbase = kvg + (size_t)tile * (32 * 512);
        // K chunks: re-read inter rows from global (L2-hot), cast to bf16
        #pragma unroll
        for (int j = 0; j < 4; ++j) {
            const int c = wave * 4 + j;            // nt = wave, kk = j
            int row = i0 + 4 * n + wave;
            bf16x8 o;
            if (row < N_ITEMS) {
                const float* p = inter + (size_t)row * HD + j * 32 + qd * 8;
                f32x4 lo = *(const f32x4*)p, hi = *(const f32x4*)(p + 4);
                o[0]=(__bf16)lo.x; o[1]=(__bf16)lo.y; o[2]=(__bf16)lo.z; o[3]=(__bf16)lo.w;
                o[4]=(__bf16)hi.x; o[5]=(__bf16)hi.y; o[6]=(__bf16)hi.z; o[7]=(__bf16)hi.w;
            } else {
                #pragma unroll
                for (int e = 0; e < 8; ++e) o[e] = (__bf16)0.f;
            }
            *(bf16x8*)(tbase + (size_t)c * 512 + lane * 8) = o;
        }
        // V chunks: from the LDS transpose
        #pragma unroll
        for (int j = 0; j < 4; ++j) {
            const int cc = wave * 4 + j;           // dt = cc>>1, kc = cc&1
            const int dt = cc >> 1, kc = cc & 1;
            bf16x8 v = *(const bf16x8*)&Tl[(dt * 16 + n) * 72 + kc * 32 + qd * 8];
            *(bf16x8*)(tbase + (size_t)(16 + cc) * 512 + lane * 8) = v;
        }
    } else {
        // ---- query path: 16 users/block; waves split the 8 output nt-tiles ----
        const int user0 = (blockIdx.x - NTILES) * 16;
        int arow = user0 + n; if (arow > N_USERS - 1) arow = N_USERS - 1;

        bf16x8 af[4];
        #pragma unroll
        for (int kk = 0; kk < 4; ++kk) {
            const float* p = ufea + (size_t)arow * HD + kk * 32 + qd * 8;
            f32x4 lo = *(const f32x4*)p, hi = *(const f32x4*)(p + 4);
            bf16x8 a;
            a[0]=(__bf16)lo.x; a[1]=(__bf16)lo.y; a[2]=(__bf16)lo.z; a[3]=(__bf16)lo.w;
            a[4]=(__bf16)hi.x; a[5]=(__bf16)hi.y; a[6]=(__bf16)hi.z; a[7]=(__bf16)hi.w;
            af[kk] = a;
        }
        #pragma unroll
        for (int h = 0; h < 2; ++h) {
            const int nt = wave * 2 + h;
            f32x4 acc = {0.f, 0.f, 0.f, 0.f};
            #pragma unroll
            for (int kk = 0; kk < 4; ++kk) {
                const float* p = W + (size_t)(nt * 16 + n) * HD + kk * 32 + qd * 8;
                f32x4 lo = *(const f32x4*)p, hi = *(const f32x4*)(p + 4);
                bf16x8 b;
                b[0]=(__bf16)lo.x; b[1]=(__bf16)lo.y; b[2]=(__bf16)lo.z; b[3]=(__bf16)lo.w;
                b[4]=(__bf16)hi.x; b[5]=(__bf16)hi.y; b[6]=(__bf16)hi.z; b[7]=(__bf16)hi.w;
                acc = __builtin_amdgcn_mfma_f32_16x16x32_bf16(af[kk], b, acc, 0, 0, 0);
            }
            const float bv = bias[nt * 16 + n];
            #pragma unroll
            for (int r = 0; r < 4; ++r) {
                int row = user0 + qd * 4 + r;      // < QROWS always
                qg[(size_t)row * HD + nt * 16 + n] = (__bf16)(acc[r] + bv);
            }
        }
    }
}

// ---------------- fused: S = q@k^T, mask+leaky+exp, O += P@V, l += rowsum ----------------
// Pipelined 2-barrier loop. Kbuf double-buffered (stage T+1 issued before QK(T));
// Vbuf single (stage T+1 issued after post-PV barrier, flies under next QK+mask).
// Wave = 32 users (two 16-user groups sharing every B-frag). adj prefetched 1 ahead.
__global__ __launch_bounds__(256, 2) void fused_kernel(const __bf16* __restrict__ qg,
                                                       const __bf16* __restrict__ kvg,
                                                       const int* __restrict__ adj,
                                                       float* __restrict__ Opart,
                                                       float* __restrict__ lpart) {
    __shared__ __bf16 Kbuf[2][16 * 512];  // double-buffered K fragment chunks
    __shared__ __bf16 Vbuf[16 * 512];     // single-buffered V fragment chunks
    __shared__ __bf16 Pl[4][32 * 72];     // per-wave P: [user 0..31][item 0..63], pitch 72
    const int lane = threadIdx.x & 63, wave = threadIdx.x >> 6;
    const int n = lane & 15, qd = lane >> 4;
    const int user0 = blockIdx.y * 128 + wave * 32;   // wave covers users user0..user0+31
    const int chunk = blockIdx.x;
    const int t0 = (chunk * NTILES) / NCHUNK;
    const int t1 = ((chunk + 1) * NTILES) / NCHUNK;
    const float SC = (float)(1.4426950408889634 * 0.08838834764831845); // log2(e)/sqrt(128)

    bf16x8 qf[2][4];
    #pragma unroll
    for (int g = 0; g < 2; ++g)
        #pragma unroll
        for (int kk = 0; kk < 4; ++kk)
            qf[g][kk] = *(const bf16x8*)(qg + (size_t)(user0 + g * 16 + n) * HD + kk * 32 + qd * 8);

    f32x4 Oacc[2][8];
    #pragma unroll
    for (int g = 0; g < 2; ++g)
        #pragma unroll
        for (int dt = 0; dt < 8; ++dt) Oacc[g][dt] = (f32x4){0.f, 0.f, 0.f, 0.f};
    float lacc[2][4] = {{0.f,0.f,0.f,0.f},{0.f,0.f,0.f,0.f}};

    int adjOff[2][4];   // element offsets (10000*12000 < 2^31)
    #pragma unroll
    for (int g = 0; g < 2; ++g)
        #pragma unroll
        for (int r = 0; r < 4; ++r) {
            int u = user0 + g * 16 + qd * 4 + r;
            if (u > N_USERS - 1) u = N_USERS - 1;
            adjOff[g][r] = u * N_ITEMS;
        }
    __bf16* pw = &Pl[wave][0];

    // ---- prologue: stage K(t0)->Kbuf[0], V(t0)->Vbuf, adj(t0)->avA ----
    i32x4 avA[2][4], avB[2][4];
    {
        const __bf16* tb = kvg + (size_t)t0 * (32 * 512);
        #pragma unroll
        for (int j = 0; j < 4; ++j) {
            const int c = wave * 4 + j;
            __builtin_amdgcn_global_load_lds((g_u32*)(tb + (size_t)c * 512 + lane * 8),
                                             (l_u32*)(&Kbuf[0][c * 512]), 16, 0, 0);
        }
        #pragma unroll
        for (int j = 0; j < 4; ++j) {
            const int c = wave * 4 + j;
            __builtin_amdgcn_global_load_lds((g_u32*)(tb + (size_t)(16 + c) * 512 + lane * 8),
                                             (l_u32*)(&Vbuf[c * 512]), 16, 0, 0);
        }
        int col4 = t0 * TILE + 4 * n;
        if (col4 > N_ITEMS - 4) col4 = N_ITEMS - 4;
        #pragma unroll
        for (int g = 0; g < 2; ++g)
            #pragma unroll
            for (int r = 0; r < 4; ++r)
                avA[g][r] = __builtin_nontemporal_load((const i32x4*)(adj + adjOff[g][r] + col4));
    }
    __syncthreads();   // drains prologue staging + adj

    auto tile_iter = [&](int T, int cur, i32x4 (&avu)[2][4], i32x4 (&avp)[2][4]) {
        const int j0 = T * TILE;
        const bool more = (T + 1 < t1);
        const __bf16* tbn = kvg + (size_t)(T + 1) * (32 * 512);

        // (1) issue K(T+1) -> Kbuf[cur^1]  (flies under QK+mask below)
        if (more) {
            #pragma unroll
            for (int j = 0; j < 4; ++j) {
                const int c = wave * 4 + j;
                __builtin_amdgcn_global_load_lds((g_u32*)(tbn + (size_t)c * 512 + lane * 8),
                                                 (l_u32*)(&Kbuf[cur ^ 1][c * 512]), 16, 0, 0);
            }
        }
        // (2) issue adj(T+1) -> avp (flies under QK+mask; drained at barrier1)
        {
            int tn = T + 1; if (tn > t1 - 1) tn = t1 - 1;
            int col4 = tn * TILE + 4 * n;
            if (col4 > N_ITEMS - 4) col4 = N_ITEMS - 4;
            #pragma unroll
            for (int g = 0; g < 2; ++g)
                #pragma unroll
                for (int r = 0; r < 4; ++r)
                    avp[g][r] = __builtin_nontemporal_load((const i32x4*)(adj + adjOff[g][r] + col4));
        }

        // (3) QK from Kbuf[cur]: 16 B-frag reads, each feeds both user groups
        f32x4 S[2][4];
        #pragma unroll
        for (int g = 0; g < 2; ++g)
            #pragma unroll
            for (int nt = 0; nt < 4; ++nt) S[g][nt] = (f32x4){0.f, 0.f, 0.f, 0.f};
        const __bf16* kb = &Kbuf[cur][0];
        #pragma unroll
        for (int nt = 0; nt < 4; ++nt) {
            #pragma unroll
            for (int kk = 0; kk < 4; ++kk) {
                bf16x8 b = *(const bf16x8*)(kb + (nt * 4 + kk) * 512 + lane * 8);
                S[0][nt] = __builtin_amdgcn_mfma_f32_16x16x32_bf16(qf[0][kk], b, S[0][nt], 0, 0, 0);
                S[1][nt] = __builtin_amdgcn_mfma_f32_16x16x32_bf16(qf[1][kk], b, S[1][nt], 0, 0, 0);
            }
        }

        // (4) mask + leaky2 + exp2 -> P quads (bf16x4 = items 4n..4n+3 of row)
        #pragma unroll
        for (int g = 0; g < 2; ++g) {
            #pragma unroll
            for (int r = 0; r < 4; ++r) {
                bf16x4 pk;
                #pragma unroll
                for (int nt = 0; nt < 4; ++nt) {
                    float s = S[g][nt][r] * SC;
                    s = fminf(s, s + s);            // leaky_relu(slope 2), pre-scaled
                    const bool on = (j0 + 4 * n + nt < N_ITEMS) && (avu[g][r][nt] > 0);
                    float p = on ? __builtin_amdgcn_exp2f(s) : 0.f;
                    lacc[g][r] += p;
                    pk[nt] = (__bf16)p;
                }
                *(bf16x4*)(pw + (g * 16 + qd * 4 + r) * 72 + 4 * n) = pk;
            }
        }

        __syncthreads();   // barrier1: drains K(T+1)+adj (flew ~1000cy); V(T) already drained

        // (6) PV from Vbuf: 16 V B-frag reads, each feeds both groups
        #pragma unroll
        for (int kc = 0; kc < 2; ++kc) {
            bf16x8 af0 = *(const bf16x8*)(pw + (0 * 16 + n) * 72 + kc * 32 + qd * 8);
            bf16x8 af1 = *(const bf16x8*)(pw + (1 * 16 + n) * 72 + kc * 32 + qd * 8);
            #pragma unroll
            for (int dt = 0; dt < 8; ++dt) {
                bf16x8 b = *(const bf16x8*)(&Vbuf[(dt * 2 + kc) * 512 + lane * 8]);
                Oacc[0][dt] = __builtin_amdgcn_mfma_f32_16x16x32_bf16(af0, b, Oacc[0][dt], 0, 0, 0);
                Oacc[1][dt] = __builtin_amdgcn_mfma_f32_16x16x32_bf16(af1, b, Oacc[1][dt], 0, 0, 0);
            }
        }

        __syncthreads();   // barrier2: all waves done PV(T) -> Vbuf free; drains nothing new

        // (8) issue V(T+1) -> Vbuf (flies under next tile's QK+mask; drained at its barrier1)
        if (more) {
            #pragma unroll
            for (int j = 0; j < 4; ++j) {
                const int c = wave * 4 + j;
                __builtin_amdgcn_global_load_lds((g_u32*)(tbn + (size_t)(16 + c) * 512 + lane * 8),
                                                 (l_u32*)(&Vbuf[c * 512]), 16, 0, 0);
            }
        }
    };

    int T = t0;
    while (true) {
        tile_iter(T, 0, avA, avB); ++T; if (T >= t1) break;
        tile_iter(T, 1, avB, avA); ++T; if (T >= t1) break;
    }

    // reduce l across the 16 lanes of each quad (lanes jointly cover all items)
    #pragma unroll
    for (int g = 0; g < 2; ++g)
        #pragma unroll
        for (int r = 0; r < 4; ++r) {
            float v = lacc[g][r];
            v += __shfl_xor(v, 1);
            v += __shfl_xor(v, 2);
            v += __shfl_xor(v, 4);
            v += __shfl_xor(v, 8);
            lacc[g][r] = v;
        }
    const size_t cb = (size_t)chunk * QROWS;
    #pragma unroll
    for (int g = 0; g < 2; ++g)
        #pragma unroll
        for (int r = 0; r < 4; ++r) {
            const int user = user0 + g * 16 + qd * 4 + r;
            if (user < N_USERS) {
                #pragma unroll
                for (int dt = 0; dt < 8; ++dt)
                    Opart[(cb + user) * HD + dt * 16 + n] = Oacc[g][dt][r];
                if (n == 0) lpart[cb + user] = lacc[g][r];
            }
        }
}

// ---------------- combine partials: out = (sum_c O_c) / (sum_c l_c) ----------------
__global__ __launch_bounds__(256) void combine_kernel(const float* __restrict__ Opart,
                                                      const float* __restrict__ lpart,
                                                      float* __restrict__ out) {
    const int g = blockIdx.x * 256 + threadIdx.x;   // 323584 threads exactly
    const int base = g * 4;
    const int user = base >> 7;
    const int d = base & 127;
    f32x4 acc = {0.f, 0.f, 0.f, 0.f};
    float l = 0.f;
    #pragma unroll
    for (int c = 0; c < NCHUNK; ++c) {
        acc += *(const f32x4*)(Opart + ((size_t)c * QROWS + user) * HD + d);
        l += lpart[(size_t)c * QROWS + user];
    }
    if (user < N_USERS) {
        f32x4 res = acc / l;
        *(f32x4*)(out + (size_t)user * HD + d) = res;
    }
}

extern "C" void kernel_launch(void* const* d_in, const int* in_sizes, int n_in,
                              void* d_out, int out_size, void* d_ws, size_t ws_size,
                              hipStream_t stream) {
    const float* ufea = (const float*)d_in[0];
    const float* inter = (const float*)d_in[1];
    const int*   adj  = (const int*)d_in[2];
    const float* W    = (const float*)d_in[3];
    const float* bias = (const float*)d_in[4];
    float* out = (float*)d_out;

    char* ws = (char*)d_ws;
    // layout (bytes):
    //   kvg   : 188*32*512*2      = 6,160,384   (tile-chunk-major K/V fragment image)
    //   qg    : 10112*128*2       = 2,588,672
    //   Opart : 12*10112*128*4    = 62,128,128
    //   lpart : 12*10112*4        = 485,376          total ~71.4 MB
    __bf16* kvg  = (__bf16*)(ws);
    __bf16* qg   = (__bf16*)(ws + 6160384);
    float*  Opart = (float*)(ws + 8749056);
    float*  lpart = (float*)(ws + 70877184);

    prep_kernel<<<dim3(NTILES + QBLOCKS), dim3(256), 0, stream>>>(inter, ufea, W, bias, kvg, qg);
    fused_kernel<<<dim3(NCHUNK, UBLOCKS), dim3(256), 0, stream>>>(qg, kvg, adj, Opart, lpart);
    combine_kernel<<<dim3(1264), dim3(256), 0, stream>>>(Opart, lpart, out);
}

// Round 4
// 663.547 us; speedup vs baseline: 1.1662x; 1.0005x over previous
//
#include <hip/hip_runtime.h>
#include <cstdint>
#include <cstddef>

// GAT forward: query = ufea@W^T + b; S = leaky2((q@inter^T)/sqrt(D)) masked by adj;
// out = softmax(S) @ inter.   N=10000 users, M=12000 items, D=128.
// R11 = R10 + T4 counted barriers (the single change this round):
//   __syncthreads() forces s_waitcnt vmcnt(0), draining the 8 in-flight adj HBM
//   loads at EVERY barrier (~1-2 HBM-latency stalls per tile). Replaced with:
//   barrier1: s_waitcnt vmcnt(8) + raw s_barrier  (waits V(T)+K(T+1) staging
//             only -- the adj(T+1) stream, always the 8 newest, stays in flight)
//   barrier2: raw s_barrier, NO vmcnt (only fences LDS buffer reuse; all
//             ds_reads already consumed by MFMAs before it)
//   sched_barrier(0) pins the asm per guide rule #18/#21.

#define N_USERS 10000
#define N_ITEMS 12000
#define HD      128
#define QROWS   10112      // 632*16 padded user rows
#define NCHUNK  12
#define TILE    64
#define NTILES  188        // ceil(12000/64); tile 187 has 32 valid items (zero-padded)
#define UBLOCKS 79         // fused user-blocks of 128
#define QBLOCKS 632        // query blocks of 16 users

typedef __bf16 bf16x8 __attribute__((ext_vector_type(8)));
typedef __bf16 bf16x4 __attribute__((ext_vector_type(4)));
typedef float  f32x4  __attribute__((ext_vector_type(4)));
typedef int    i32x4  __attribute__((ext_vector_type(4)));

typedef const __attribute__((address_space(1))) unsigned int g_u32;
typedef __attribute__((address_space(3))) unsigned int l_u32;

// ---------------- prep: inter -> kvg fragment image  +  query = ufea@W^T + b ----------------
// kvg layout per tile t (32KB): 32 chunks x 512 halves.
//   chunk c<16  (K): c=nt*4+kk, element[lane= qd*16+n][e] = K[t*64 + 4n+nt][kk*32+qd*8+e]
//   chunk 16+cc (V): cc=dt*2+kc, element[lane][e]        = inter[t*64+kc*32+qd*8+e][dt*16+n]
// Invalid items (>=12000) zero-filled -> fused needs no row clamps for K/V.
__global__ __launch_bounds__(256) void prep_kernel(const float* __restrict__ inter,
                                                   const float* __restrict__ ufea,
                                                   const float* __restrict__ W,
                                                   const float* __restrict__ bias,
                                                   __bf16* __restrict__ kvg,
                                                   __bf16* __restrict__ qg) {
    __shared__ __bf16 Tl[128 * 72];   // [d][item_local], pitch 72 (16B-aligned rows)
    const int t = threadIdx.x;
    const int lane = t & 63, wave = t >> 6;
    const int n = lane & 15, qd = lane >> 4;

    if (blockIdx.x < NTILES) {
        // ---- cast path ----
        const int tile = blockIdx.x;
        const int i0 = tile * 64;
        for (int it = 0; it < 8; ++it) {
            int g   = it * 256 + t;
            int row = g >> 5;            // 0..63 item_local
            int d   = (g & 31) * 4;      // 0..124
            int item = i0 + row;
            if (item < N_ITEMS) {
                f32x4 v = *(const f32x4*)(inter + (size_t)item * HD + d);
                Tl[(d + 0) * 72 + row] = (__bf16)v.x;
                Tl[(d + 1) * 72 + row] = (__bf16)v.y;
                Tl[(d + 2) * 72 + row] = (__bf16)v.z;
                Tl[(d + 3) * 72 + row] = (__bf16)v.w;
            } else {
                Tl[(d + 0) * 72 + row] = (__bf16)0.f;
                Tl[(d + 1) * 72 + row] = (__bf16)0.f;
                Tl[(d + 2) * 72 + row] = (__bf16)0.f;
                Tl[(d + 3) * 72 + row] = (__bf16)0.f;
            }
        }
        __syncthreads();
        __bf16* tbase = kvg + (size_t)tile * (32 * 512);
        // K chunks: re-read inter rows from global (L2-hot), cast to bf16
        #pragma unroll
        for (int j = 0; j < 4; ++j) {
            const int c = wave * 4 + j;            // nt = wave, kk = j
            int row = i0 + 4 * n + wave;
            bf16x8 o;
            if (row < N_ITEMS) {
                const float* p = inter + (size_t)row * HD + j * 32 + qd * 8;
                f32x4 lo = *(const f32x4*)p, hi = *(const f32x4*)(p + 4);
                o[0]=(__bf16)lo.x; o[1]=(__bf16)lo.y; o[2]=(__bf16)lo.z; o[3]=(__bf16)lo.w;
                o[4]=(__bf16)hi.x; o[5]=(__bf16)hi.y; o[6]=(__bf16)hi.z; o[7]=(__bf16)hi.w;
            } else {
                #pragma unroll
                for (int e = 0; e < 8; ++e) o[e] = (__bf16)0.f;
            }
            *(bf16x8*)(tbase + (size_t)c * 512 + lane * 8) = o;
        }
        // V chunks: from the LDS transpose
        #pragma unroll
        for (int j = 0; j < 4; ++j) {
            const int cc = wave * 4 + j;           // dt = cc>>1, kc = cc&1
            const int dt = cc >> 1, kc = cc & 1;
            bf16x8 v = *(const bf16x8*)&Tl[(dt * 16 + n) * 72 + kc * 32 + qd * 8];
            *(bf16x8*)(tbase + (size_t)(16 + cc) * 512 + lane * 8) = v;
        }
    } else {
        // ---- query path: 16 users/block; waves split the 8 output nt-tiles ----
        const int user0 = (blockIdx.x - NTILES) * 16;
        int arow = user0 + n; if (arow > N_USERS - 1) arow = N_USERS - 1;

        bf16x8 af[4];
        #pragma unroll
        for (int kk = 0; kk < 4; ++kk) {
            const float* p = ufea + (size_t)arow * HD + kk * 32 + qd * 8;
            f32x4 lo = *(const f32x4*)p, hi = *(const f32x4*)(p + 4);
            bf16x8 a;
            a[0]=(__bf16)lo.x; a[1]=(__bf16)lo.y; a[2]=(__bf16)lo.z; a[3]=(__bf16)lo.w;
            a[4]=(__bf16)hi.x; a[5]=(__bf16)hi.y; a[6]=(__bf16)hi.z; a[7]=(__bf16)hi.w;
            af[kk] = a;
        }
        #pragma unroll
        for (int h = 0; h < 2; ++h) {
            const int nt = wave * 2 + h;
            f32x4 acc = {0.f, 0.f, 0.f, 0.f};
            #pragma unroll
            for (int kk = 0; kk < 4; ++kk) {
                const float* p = W + (size_t)(nt * 16 + n) * HD + kk * 32 + qd * 8;
                f32x4 lo = *(const f32x4*)p, hi = *(const f32x4*)(p + 4);
                bf16x8 b;
                b[0]=(__bf16)lo.x; b[1]=(__bf16)lo.y; b[2]=(__bf16)lo.z; b[3]=(__bf16)lo.w;
                b[4]=(__bf16)hi.x; b[5]=(__bf16)hi.y; b[6]=(__bf16)hi.z; b[7]=(__bf16)hi.w;
                acc = __builtin_amdgcn_mfma_f32_16x16x32_bf16(af[kk], b, acc, 0, 0, 0);
            }
            const float bv = bias[nt * 16 + n];
            #pragma unroll
            for (int r = 0; r < 4; ++r) {
                int row = user0 + qd * 4 + r;      // < QROWS always
                qg[(size_t)row * HD + nt * 16 + n] = (__bf16)(acc[r] + bv);
            }
        }
    }
}

// ---------------- fused: S = q@k^T, mask+leaky+exp, O += P@V, l += rowsum ----------------
// Pipelined loop with counted barriers. Kbuf double-buffered (stage T+1 issued
// before QK(T)); Vbuf single (stage T+1 issued after barrier2, flies under next
// tile's QK+mask). adj prefetched 1 tile ahead and NEVER drained by a barrier.
__global__ __launch_bounds__(256, 2) void fused_kernel(const __bf16* __restrict__ qg,
                                                       const __bf16* __restrict__ kvg,
                                                       const int* __restrict__ adj,
                                                       float* __restrict__ Opart,
                                                       float* __restrict__ lpart) {
    __shared__ __bf16 Kbuf[2][16 * 512];  // double-buffered K fragment chunks
    __shared__ __bf16 Vbuf[16 * 512];     // single-buffered V fragment chunks
    __shared__ __bf16 Pl[4][32 * 72];     // per-wave P: [user 0..31][item 0..63], pitch 72
    const int lane = threadIdx.x & 63, wave = threadIdx.x >> 6;
    const int n = lane & 15, qd = lane >> 4;
    const int user0 = blockIdx.y * 128 + wave * 32;   // wave covers users user0..user0+31
    const int chunk = blockIdx.x;
    const int t0 = (chunk * NTILES) / NCHUNK;
    const int t1 = ((chunk + 1) * NTILES) / NCHUNK;
    const float SC = (float)(1.4426950408889634 * 0.08838834764831845); // log2(e)/sqrt(128)

    bf16x8 qf[2][4];
    #pragma unroll
    for (int g = 0; g < 2; ++g)
        #pragma unroll
        for (int kk = 0; kk < 4; ++kk)
            qf[g][kk] = *(const bf16x8*)(qg + (size_t)(user0 + g * 16 + n) * HD + kk * 32 + qd * 8);

    f32x4 Oacc[2][8];
    #pragma unroll
    for (int g = 0; g < 2; ++g)
        #pragma unroll
        for (int dt = 0; dt < 8; ++dt) Oacc[g][dt] = (f32x4){0.f, 0.f, 0.f, 0.f};
    float lacc[2][4] = {{0.f,0.f,0.f,0.f},{0.f,0.f,0.f,0.f}};

    int adjOff[2][4];   // element offsets (10000*12000 < 2^31)
    #pragma unroll
    for (int g = 0; g < 2; ++g)
        #pragma unroll
        for (int r = 0; r < 4; ++r) {
            int u = user0 + g * 16 + qd * 4 + r;
            if (u > N_USERS - 1) u = N_USERS - 1;
            adjOff[g][r] = u * N_ITEMS;
        }
    __bf16* pw = &Pl[wave][0];

    // ---- prologue: stage K(t0)->Kbuf[0], V(t0)->Vbuf, adj(t0)->avA ----
    i32x4 avA[2][4], avB[2][4];
    {
        const __bf16* tb = kvg + (size_t)t0 * (32 * 512);
        #pragma unroll
        for (int j = 0; j < 4; ++j) {
            const int c = wave * 4 + j;
            __builtin_amdgcn_global_load_lds((g_u32*)(tb + (size_t)c * 512 + lane * 8),
                                             (l_u32*)(&Kbuf[0][c * 512]), 16, 0, 0);
        }
        #pragma unroll
        for (int j = 0; j < 4; ++j) {
            const int c = wave * 4 + j;
            __builtin_amdgcn_global_load_lds((g_u32*)(tb + (size_t)(16 + c) * 512 + lane * 8),
                                             (l_u32*)(&Vbuf[c * 512]), 16, 0, 0);
        }
        int col4 = t0 * TILE + 4 * n;
        if (col4 > N_ITEMS - 4) col4 = N_ITEMS - 4;
        #pragma unroll
        for (int g = 0; g < 2; ++g)
            #pragma unroll
            for (int r = 0; r < 4; ++r)
                avA[g][r] = __builtin_nontemporal_load((const i32x4*)(adj + adjOff[g][r] + col4));
    }
    __syncthreads();   // prologue: full drain once (staging + adj(t0))

    auto tile_iter = [&](int T, int cur, i32x4 (&avu)[2][4], i32x4 (&avp)[2][4]) {
        const int j0 = T * TILE;
        const bool more = (T + 1 < t1);
        const __bf16* tbn = kvg + (size_t)(T + 1) * (32 * 512);

        // (1) issue K(T+1) -> Kbuf[cur^1]  (drained by barrier1's vmcnt(8))
        if (more) {
            #pragma unroll
            for (int j = 0; j < 4; ++j) {
                const int c = wave * 4 + j;
                __builtin_amdgcn_global_load_lds((g_u32*)(tbn + (size_t)c * 512 + lane * 8),
                                                 (l_u32*)(&Kbuf[cur ^ 1][c * 512]), 16, 0, 0);
            }
        }
        // (2) issue adj(T+1) -> avp (stays in flight across BOTH barriers; the
        //     compiler's register-dep wait covers its consumption next tile)
        {
            int tn = T + 1; if (tn > t1 - 1) tn = t1 - 1;
            int col4 = tn * TILE + 4 * n;
            if (col4 > N_ITEMS - 4) col4 = N_ITEMS - 4;
            #pragma unroll
            for (int g = 0; g < 2; ++g)
                #pragma unroll
                for (int r = 0; r < 4; ++r)
                    avp[g][r] = __builtin_nontemporal_load((const i32x4*)(adj + adjOff[g][r] + col4));
        }

        // (3) QK from Kbuf[cur]: 16 B-frag reads, each feeds both user groups
        f32x4 S[2][4];
        #pragma unroll
        for (int g = 0; g < 2; ++g)
            #pragma unroll
            for (int nt = 0; nt < 4; ++nt) S[g][nt] = (f32x4){0.f, 0.f, 0.f, 0.f};
        const __bf16* kb = &Kbuf[cur][0];
        #pragma unroll
        for (int nt = 0; nt < 4; ++nt) {
            #pragma unroll
            for (int kk = 0; kk < 4; ++kk) {
                bf16x8 b = *(const bf16x8*)(kb + (nt * 4 + kk) * 512 + lane * 8);
                S[0][nt] = __builtin_amdgcn_mfma_f32_16x16x32_bf16(qf[0][kk], b, S[0][nt], 0, 0, 0);
                S[1][nt] = __builtin_amdgcn_mfma_f32_16x16x32_bf16(qf[1][kk], b, S[1][nt], 0, 0, 0);
            }
        }

        // (4) mask + leaky2 + exp2 -> P quads (bf16x4 = items 4n..4n+3 of row)
        #pragma unroll
        for (int g = 0; g < 2; ++g) {
            #pragma unroll
            for (int r = 0; r < 4; ++r) {
                bf16x4 pk;
                #pragma unroll
                for (int nt = 0; nt < 4; ++nt) {
                    float s = S[g][nt][r] * SC;
                    s = fminf(s, s + s);            // leaky_relu(slope 2), pre-scaled
                    const bool on = (j0 + 4 * n + nt < N_ITEMS) && (avu[g][r][nt] > 0);
                    float p = on ? __builtin_amdgcn_exp2f(s) : 0.f;
                    lacc[g][r] += p;
                    pk[nt] = (__bf16)p;
                }
                *(bf16x4*)(pw + (g * 16 + qd * 4 + r) * 72 + 4 * n) = pk;
            }
        }

        // barrier1 (counted): wait V(T)+K(T+1) staging (8 oldest), keep the 8
        // adj(T+1) loads in flight. Raw s_barrier: no implicit vmcnt(0).
        __builtin_amdgcn_sched_barrier(0);
        __asm__ volatile("s_waitcnt vmcnt(8)" ::: "memory");
        __builtin_amdgcn_sched_barrier(0);
        __builtin_amdgcn_s_barrier();
        __builtin_amdgcn_sched_barrier(0);

        // (6) PV from Vbuf: 16 V B-frag reads, each feeds both groups
        #pragma unroll
        for (int kc = 0; kc < 2; ++kc) {
            bf16x8 af0 = *(const bf16x8*)(pw + (0 * 16 + n) * 72 + kc * 32 + qd * 8);
            bf16x8 af1 = *(const bf16x8*)(pw + (1 * 16 + n) * 72 + kc * 32 + qd * 8);
            #pragma unroll
            for (int dt = 0; dt < 8; ++dt) {
                bf16x8 b = *(const bf16x8*)(&Vbuf[(dt * 2 + kc) * 512 + lane * 8]);
                Oacc[0][dt] = __builtin_amdgcn_mfma_f32_16x16x32_bf16(af0, b, Oacc[0][dt], 0, 0, 0);
                Oacc[1][dt] = __builtin_amdgcn_mfma_f32_16x16x32_bf16(af1, b, Oacc[1][dt], 0, 0, 0);
            }
        }

        // barrier2: fences Vbuf/Kbuf[cur] reuse only. All ds_reads were consumed
        // by MFMAs above (compiler lgkm waits); NO vmcnt drain here.
        __builtin_amdgcn_sched_barrier(0);
        __builtin_amdgcn_s_barrier();
        __builtin_amdgcn_sched_barrier(0);

        // (8) issue V(T+1) -> Vbuf (drained by next tile's barrier1 vmcnt(8))
        if (more) {
            #pragma unroll
            for (int j = 0; j < 4; ++j) {
                const int c = wave * 4 + j;
                __builtin_amdgcn_global_load_lds((g_u32*)(tbn + (size_t)(16 + c) * 512 + lane * 8),
                                                 (l_u32*)(&Vbuf[c * 512]), 16, 0, 0);
            }
        }
    };

    int T = t0;
    while (true) {
        tile_iter(T, 0, avA, avB); ++T; if (T >= t1) break;
        tile_iter(T, 1, avB, avA); ++T; if (T >= t1) break;
    }

    // reduce l across the 16 lanes of each quad (lanes jointly cover all items)
    #pragma unroll
    for (int g = 0; g < 2; ++g)
        #pragma unroll
        for (int r = 0; r < 4; ++r) {
            float v = lacc[g][r];
            v += __shfl_xor(v, 1);
            v += __shfl_xor(v, 2);
            v += __shfl_xor(v, 4);
            v += __shfl_xor(v, 8);
            lacc[g][r] = v;
        }
    const size_t cb = (size_t)chunk * QROWS;
    #pragma unroll
    for (int g = 0; g < 2; ++g)
        #pragma unroll
        for (int r = 0; r < 4; ++r) {
            const int user = user0 + g * 16 + qd * 4 + r;
            if (user < N_USERS) {
                #pragma unroll
                for (int dt = 0; dt < 8; ++dt)
                    Opart[(cb + user) * HD + dt * 16 + n] = Oacc[g][dt][r];
                if (n == 0) lpart[cb + user] = lacc[g][r];
            }
        }
}

// ---------------- combine partials: out = (sum_c O_c) / (sum_c l_c) ----------------
__global__ __launch_bounds__(256) void combine_kernel(const float* __restrict__ Opart,
                                                      const float* __restrict__ lpart,
                                                      float* __restrict__ out) {
    const int g = blockIdx.x * 256 + threadIdx.x;   // 323584 threads exactly
    const int base = g * 4;
    const int user = base >> 7;
    const int d = base & 127;
    f32x4 acc = {0.f, 0.f, 0.f, 0.f};
    float l = 0.f;
    #pragma unroll
    for (int c = 0; c < NCHUNK; ++c) {
        acc += *(const f32x4*)(Opart + ((size_t)c * QROWS + user) * HD + d);
        l += lpart[(size_t)c * QROWS + user];
    }
    if (user < N_USERS) {
        f32x4 res = acc / l;
        *(f32x4*)(out + (size_t)user * HD + d) = res;
    }
}

extern "C" void kernel_launch(void* const* d_in, const int* in_sizes, int n_in,
                              void* d_out, int out_size, void* d_ws, size_t ws_size,
                              hipStream_t stream) {
    const float* ufea = (const float*)d_in[0];
    const float* inter = (const float*)d_in[1];
    const int*   adj  = (const int*)d_in[2];
    const float* W    = (const float*)d_in[3];
    const float* bias = (const float*)d_in[4];
    float* out = (float*)d_out;

    char* ws = (char*)d_ws;
    // layout (bytes):
    //   kvg   : 188*32*512*2      = 6,160,384   (tile-chunk-major K/V fragment image)
    //   qg    : 10112*128*2       = 2,588,672
    //   Opart : 12*10112*128*4    = 62,128,128
    //   lpart : 12*10112*4        = 485,376          total ~71.4 MB
    __bf16* kvg  = (__bf16*)(ws);
    __bf16* qg   = (__bf16*)(ws + 6160384);
    float*  Opart = (float*)(ws + 8749056);
    float*  lpart = (float*)(ws + 70877184);

    prep_kernel<<<dim3(NTILES + QBLOCKS), dim3(256), 0, stream>>>(inter, ufea, W, bias, kvg, qg);
    fused_kernel<<<dim3(NCHUNK, UBLOCKS), dim3(256), 0, stream>>>(qg, kvg, adj, Opart, lpart);
    combine_kernel<<<dim3(1264), dim3(256), 0, stream>>>(Opart, lpart, out);
}